// Round 3
// baseline (239.207 us; speedup 1.0000x reference)
//
#include <hip/hip_runtime.h>
#include <hip/hip_bf16.h>
#include <stdint.h>
#include <stddef.h>

typedef __hip_bfloat16 bf16;
typedef __attribute__((ext_vector_type(8))) short short8;   // 8 bf16 = 4 VGPRs
typedef __attribute__((ext_vector_type(4))) float floatx4;  // MFMA 16x16 accumulator

// async global->LDS, 16 B per lane. LDS dest must be wave-uniform base + lane*16.
__device__ __forceinline__ void async_load16(const bf16* g, bf16* l) {
#if defined(__has_builtin) && __has_builtin(__builtin_amdgcn_global_load_lds)
  __builtin_amdgcn_global_load_lds((__attribute__((address_space(1))) void*)g,
                                   (__attribute__((address_space(3))) void*)l,
                                   16, 0, 0);
#else
  *(short8*)l = *(const short8*)g;
#endif
}

// ---------------------------------------------------------------------------
// Wave-local input dtype detection (f32 vs bf16).
// ---------------------------------------------------------------------------
__device__ __forceinline__ int wave_detect_f32(const unsigned short* __restrict__ xr) {
  const int lane = threadIdx.x & 63;
  const unsigned short u = xr[lane];
  const int e = (u >> 7) & 0xFF;
  const unsigned long long m = __ballot(e >= 0x93);
  return (__popcll(m) > 5) ? 1 : 0;
}

// ---------------------------------------------------------------------------
// Fused prep v2: 8-wide canon, 4-wide weff (4x fewer VMEM ops/element).
// ---------------------------------------------------------------------------
struct PrepArgs {
  const void *x, *ft, *bq, *bf, *bp;
  const void *Wq, *Aq, *Bq, *Wf, *Af, *Bf, *Wp, *Ap, *Bp;
  bf16 *cx, *cft, *cbq, *cbf, *cbp, *weffq, *wefff, *weffp;
};

__device__ __forceinline__ void canon8(const void* src, bf16* dst, int i8, int flg) {
  if (flg) {
    const float4 v0 = ((const float4*)src)[i8 * 2];
    const float4 v1 = ((const float4*)src)[i8 * 2 + 1];
    bf16 o[8];
    o[0] = __float2bfloat16(v0.x); o[1] = __float2bfloat16(v0.y);
    o[2] = __float2bfloat16(v0.z); o[3] = __float2bfloat16(v0.w);
    o[4] = __float2bfloat16(v1.x); o[5] = __float2bfloat16(v1.y);
    o[6] = __float2bfloat16(v1.z); o[7] = __float2bfloat16(v1.w);
    *(uint4*)(dst + i8 * 8) = *(const uint4*)o;
  } else {
    ((uint4*)dst)[i8] = ((const uint4*)src)[i8];
  }
}

// Weff[n][k..k+3] = W + (1/16) * B[n][:] . A[:][k..k+3].  B row is block-uniform.
__device__ __forceinline__ void weff4(const void* W, const void* Bm, const void* Am,
                                      bf16* dst, int idx4, int flg) {
  const int n = idx4 >> 8, k = (idx4 & 255) << 2;
  float a0 = 0.f, a1 = 0.f, a2 = 0.f, a3 = 0.f;
  float w0, w1, w2, w3;
  if (flg) {
    const float* Af = (const float*)Am;
    const float* Bf = (const float*)Bm;
#pragma unroll
    for (int r = 0; r < 16; ++r) {
      const float4 av = *(const float4*)(Af + r * 1024 + k);
      const float bv = Bf[n * 16 + r];
      a0 += bv * av.x; a1 += bv * av.y; a2 += bv * av.z; a3 += bv * av.w;
    }
    const float4 wv = *(const float4*)((const float*)W + n * 1024 + k);
    w0 = wv.x; w1 = wv.y; w2 = wv.z; w3 = wv.w;
  } else {
    const bf16* Ab = (const bf16*)Am;
    const bf16* Bb = (const bf16*)Bm;
#pragma unroll
    for (int r = 0; r < 16; ++r) {
      const float bv = __bfloat162float(Bb[n * 16 + r]);
      const bf16* ap = Ab + r * 1024 + k;
      a0 += bv * __bfloat162float(ap[0]);
      a1 += bv * __bfloat162float(ap[1]);
      a2 += bv * __bfloat162float(ap[2]);
      a3 += bv * __bfloat162float(ap[3]);
    }
    const bf16* Wb = (const bf16*)W + n * 1024 + k;
    w0 = __bfloat162float(Wb[0]); w1 = __bfloat162float(Wb[1]);
    w2 = __bfloat162float(Wb[2]); w3 = __bfloat162float(Wb[3]);
  }
  bf16 o[4];
  o[0] = __float2bfloat16(w0 + 0.0625f * a0);
  o[1] = __float2bfloat16(w1 + 0.0625f * a1);
  o[2] = __float2bfloat16(w2 + 0.0625f * a2);
  o[3] = __float2bfloat16(w3 + 0.0625f * a3);
  *(uint2*)(dst + idx4 * 4) = *(const uint2*)o;
}

// blocks: [0,4096) cx | [4096,5120) cft | [5120,5122) biases |
//         [5122,6146) weffq | [6146,8194) wefff | [8194,9218) weffp
__global__ __launch_bounds__(256) void prep_kernel(PrepArgs a) {
  const int flg = wave_detect_f32((const unsigned short*)a.x);
  const int bid = blockIdx.x, tid = threadIdx.x;
  if (bid < 4096) {
    canon8(a.x, a.cx, bid * 256 + tid, flg);
  } else if (bid < 5120) {
    canon8(a.ft, a.cft, (bid - 4096) * 256 + tid, flg);
  } else if (bid < 5122) {
    const int e8 = (bid - 5120) * 256 + tid;   // 512 threads cover 4096 bias elems
    if (e8 < 128) canon8(a.bq, a.cbq, e8, flg);
    else if (e8 < 384) canon8(a.bf, a.cbf, e8 - 128, flg);
    else canon8(a.bp, a.cbp, e8 - 384, flg);
  } else if (bid < 6146) {
    weff4(a.Wq, a.Bq, a.Aq, a.weffq, (bid - 5122) * 256 + tid, flg);
  } else if (bid < 8194) {
    weff4(a.Wf, a.Bf, a.Af, a.wefff, (bid - 6146) * 256 + tid, flg);
  } else {
    weff4(a.Wp, a.Bp, a.Ap, a.weffp, (bid - 8194) * 256 + tid, flg);
  }
}

// ---------------------------------------------------------------------------
// GEMM core v4 (proven-quadrant structure): 256-wide tiles, BK=32, 8 waves
// (512 thr), 4-slot LDS ring, stage-lead 3, counted vmcnt (never 0 in steady
// state), raw s_barrier, both-sides XOR chunk swizzle (chunk ^= (row>>1)&3 —
// the involution verified conflict-free in round 2), setprio around the MFMA
// cluster. 32 MFMA per wave per barrier-pair (2x m201's per-phase density).
//
// Ring invariants (tile t in slot t&3):
//   - stage at iter t targets slot (t+3)&3, which held tile t-1, whose reads
//     retired before this iter's lgkmcnt(0)+barrier(A).
//   - vmcnt(12) leaves tiles t+1..t+3 (4 loads each) in flight; tile t
//     confirmed. barrier(B) publishes it to all 8 waves.
//   - tile-t loads issued at iter t-3 -> 3 compute phases of latency budget.
// ---------------------------------------------------------------------------
#define QSLOT (256 * 32)          // one 256x32 bf16 panel
#define RSLOT (2 * QSLOT)         // A panel + B panel = 32 KB

__device__ __forceinline__ void stage256(const bf16* __restrict__ gA,
                                         const bf16* __restrict__ gB,
                                         bf16* slot, int tid) {
  // A: 256 rows x 4 chunks(16B) = 1024 chunks, 2/thread. LDS linear, global
  // source pre-swizzled: phys chunk p of row r holds logical chunk p^((r>>1)&3).
#pragma unroll
  for (int l = 0; l < 2; ++l) {
    const int D = l * 512 + tid;
    const int r = D >> 2;
    const int c = (D & 3) ^ ((r >> 1) & 3);
    async_load16(gA + (size_t)r * 1024 + c * 8, slot + D * 8);
  }
#pragma unroll
  for (int l = 0; l < 2; ++l) {
    const int D = l * 512 + tid;
    const int r = D >> 2;
    const int c = (D & 3) ^ ((r >> 1) & 3);
    async_load16(gB + (size_t)r * 1024 + c * 8, slot + QSLOT + D * 8);
  }
}

__device__ __forceinline__ void gemm_core256(const bf16* __restrict__ A,
                                             const bf16* __restrict__ Bt,
                                             int bm, int bn, bf16* sT,
                                             floatx4 (&acc)[8][4]) {
  const int tid = threadIdx.x;
  const int wave = tid >> 6, lane = tid & 63;
  const int lrow = lane & 15, quad = lane >> 4;
  const int wm = (wave >> 2) << 7;      // 2 waves along M: 0,128
  const int wn = (wave & 3) << 6;       // 4 waves along N: 0..192
  const int pc0 = ((quad ^ ((lrow >> 1) & 3)) << 3);  // matching frag-read XOR

  const bf16* gA = A + (size_t)bm * 1024;
  const bf16* gB = Bt + (size_t)bn * 1024;

  stage256(gA,      gB,      sT,             tid);   // tile 0 -> slot 0
  stage256(gA + 32, gB + 32, sT + RSLOT,     tid);   // tile 1 -> slot 1
  stage256(gA + 64, gB + 64, sT + 2 * RSLOT, tid);   // tile 2 -> slot 2

#pragma unroll 4
  for (int t = 0; t < 32; ++t) {
    asm volatile("s_waitcnt lgkmcnt(0)" ::: "memory");
    __builtin_amdgcn_s_barrier();
    __builtin_amdgcn_sched_barrier(0);
    if (t < 29) {
      stage256(gA + (t + 3) * 32, gB + (t + 3) * 32, sT + ((t + 3) & 3) * RSLOT, tid);
      asm volatile("s_waitcnt vmcnt(12)" ::: "memory");
    } else if (t == 29) {
      asm volatile("s_waitcnt vmcnt(8)" ::: "memory");
    } else if (t == 30) {
      asm volatile("s_waitcnt vmcnt(4)" ::: "memory");
    } else {
      asm volatile("s_waitcnt vmcnt(0)" ::: "memory");
    }
    __builtin_amdgcn_s_barrier();
    __builtin_amdgcn_sched_barrier(0);

    const bf16* slotA = sT + (t & 3) * RSLOT;
    const bf16* slotB = slotA + QSLOT;
    short8 a_[8], b_[4];
#pragma unroll
    for (int i = 0; i < 8; ++i)
      a_[i] = *(const short8*)(slotA + (wm + i * 16 + lrow) * 32 + pc0);
#pragma unroll
    for (int j = 0; j < 4; ++j)
      b_[j] = *(const short8*)(slotB + (wn + j * 16 + lrow) * 32 + pc0);
    __builtin_amdgcn_s_setprio(1);
#pragma unroll
    for (int i = 0; i < 8; ++i)
#pragma unroll
      for (int j = 0; j < 4; ++j)
        acc[i][j] = __builtin_amdgcn_mfma_f32_16x16x32_bf16(
            a_[i], b_[j], acc[i][j], 0, 0, 0);
    __builtin_amdgcn_s_setprio(0);
  }
}

// 256x128 variant for gemm_out (256 blocks = exactly 1/CU). Waves 4M x 2N.
#define QSLOTB (128 * 32)
#define RSLOTO (QSLOT + QSLOTB)   // 24 KB

__device__ __forceinline__ void stage128(const bf16* __restrict__ gA,
                                         const bf16* __restrict__ gB,
                                         bf16* slot, int tid) {
#pragma unroll
  for (int l = 0; l < 2; ++l) {
    const int D = l * 512 + tid;
    const int r = D >> 2;
    const int c = (D & 3) ^ ((r >> 1) & 3);
    async_load16(gA + (size_t)r * 1024 + c * 8, slot + D * 8);
  }
  {
    const int D = tid;                 // B: 128 rows x 4 chunks = 512 chunks
    const int r = D >> 2;
    const int c = (D & 3) ^ ((r >> 1) & 3);
    async_load16(gB + (size_t)r * 1024 + c * 8, slot + QSLOT + D * 8);
  }
}

__device__ __forceinline__ void gemm_core128(const bf16* __restrict__ A,
                                             const bf16* __restrict__ Bt,
                                             int bm, int bn, bf16* sT,
                                             floatx4 (&acc)[4][4]) {
  const int tid = threadIdx.x;
  const int wave = tid >> 6, lane = tid & 63;
  const int lrow = lane & 15, quad = lane >> 4;
  const int wm = (wave >> 1) << 6;      // 4 waves along M: 0..192
  const int wn = (wave & 1) << 6;       // 2 waves along N: 0,64
  const int pc0 = ((quad ^ ((lrow >> 1) & 3)) << 3);

  const bf16* gA = A + (size_t)bm * 1024;
  const bf16* gB = Bt + (size_t)bn * 1024;

  stage128(gA,      gB,      sT,             tid);
  stage128(gA + 32, gB + 32, sT + RSLOTO,     tid);
  stage128(gA + 64, gB + 64, sT + 2 * RSLOTO, tid);

#pragma unroll 4
  for (int t = 0; t < 32; ++t) {
    asm volatile("s_waitcnt lgkmcnt(0)" ::: "memory");
    __builtin_amdgcn_s_barrier();
    __builtin_amdgcn_sched_barrier(0);
    if (t < 29) {
      stage128(gA + (t + 3) * 32, gB + (t + 3) * 32, sT + ((t + 3) & 3) * RSLOTO, tid);
      asm volatile("s_waitcnt vmcnt(9)" ::: "memory");
    } else if (t == 29) {
      asm volatile("s_waitcnt vmcnt(6)" ::: "memory");
    } else if (t == 30) {
      asm volatile("s_waitcnt vmcnt(3)" ::: "memory");
    } else {
      asm volatile("s_waitcnt vmcnt(0)" ::: "memory");
    }
    __builtin_amdgcn_s_barrier();
    __builtin_amdgcn_sched_barrier(0);

    const bf16* slotA = sT + (t & 3) * RSLOTO;
    const bf16* slotB = slotA + QSLOT;
    short8 a_[4], b_[4];
#pragma unroll
    for (int i = 0; i < 4; ++i) {
      a_[i] = *(const short8*)(slotA + (wm + i * 16 + lrow) * 32 + pc0);
      b_[i] = *(const short8*)(slotB + (wn + i * 16 + lrow) * 32 + pc0);
    }
    __builtin_amdgcn_s_setprio(1);
#pragma unroll
    for (int i = 0; i < 4; ++i)
#pragma unroll
      for (int j = 0; j < 4; ++j)
        acc[i][j] = __builtin_amdgcn_mfma_f32_16x16x32_bf16(
            a_[i], b_[j], acc[i][j], 0, 0, 0);
    __builtin_amdgcn_s_setprio(0);
  }
}

// ---------------------------------------------------------------------------
// Fused q-proj + kv-proj GEMM: 192 blocks (q 32x4 + kv 8x8 of 256x256),
// bijective chunked XCD swizzle (192 % 8 == 0).
// ---------------------------------------------------------------------------
__global__ __launch_bounds__(512, 1) void gemm_qkv(
    const bf16* __restrict__ cx, const bf16* __restrict__ cft,
    const bf16* __restrict__ weffq, const bf16* __restrict__ wefff,
    const bf16* __restrict__ cbq, const bf16* __restrict__ cbf,
    bf16* __restrict__ qws, bf16* __restrict__ kws, bf16* __restrict__ vtws) {
  __shared__ __align__(16) bf16 sT[4 * RSLOT];   // 128 KB
  const int bid = blockIdx.x;
  const int swz = (bid & 7) * 24 + (bid >> 3);   // 8 XCDs x 24 contiguous blocks
  int mode, bm, bn;
  const bf16 *A, *Bt, *bias;
  if (swz < 128) {
    mode = 0; A = cx; Bt = weffq; bias = cbq;
    bm = (swz >> 2) * 256; bn = (swz & 3) * 256;
  } else {
    const int s2 = swz - 128;
    mode = 1; A = cft; Bt = wefff; bias = cbf;
    bm = (s2 >> 3) * 256; bn = (s2 & 7) * 256;
  }

  const floatx4 zero4 = {0.f, 0.f, 0.f, 0.f};
  floatx4 acc[8][4];
#pragma unroll
  for (int i = 0; i < 8; ++i)
#pragma unroll
    for (int j = 0; j < 4; ++j) acc[i][j] = zero4;

  gemm_core256(A, Bt, bm, bn, sT, acc);

  const int tid = threadIdx.x, wave = tid >> 6, lane = tid & 63;
  const int lrow = lane & 15, quad = lane >> 4;
  const int wm = (wave >> 2) << 7, wn = (wave & 3) << 6;
#pragma unroll
  for (int i = 0; i < 8; ++i) {
    const int mbase = bm + wm + i * 16 + quad * 4;
#pragma unroll
    for (int j = 0; j < 4; ++j) {
      const int n = bn + wn + j * 16 + lrow;
      const float bv = __bfloat162float(bias[n]);
#pragma unroll
      for (int r = 0; r < 4; ++r) {
        const int m = mbase + r;
        const bf16 hval = __float2bfloat16(acc[i][j][r] + bv);
        if (mode == 0) {
          const int b = m >> 10, t = m & 1023, hh = n >> 6, d = n & 63;
          qws[(((size_t)(b * 16 + hh)) * 1024 + t) * 64 + d] = hval;
        } else {
          const int b = m >> 8, s = m & 255;
          if (n < 1024) {
            const int hh = n >> 6, d = n & 63;
            kws[(((size_t)(b * 16 + hh)) * 256 + s) * 64 + d] = hval;
          } else {
            const int nn = n - 1024, hh = nn >> 6, d = nn & 63;
            vtws[(((size_t)(b * 16 + hh)) * 64 + d) * 256 + s] = hval;
          }
        }
      }
    }
  }
}

// ---------------------------------------------------------------------------
// Out-proj GEMM: 256 blocks (32x8 of 256x128) = exactly 1/CU, XCD-swizzled.
// ---------------------------------------------------------------------------
__global__ __launch_bounds__(512, 1) void gemm_out(
    const bf16* __restrict__ A, const bf16* __restrict__ Bt,
    const bf16* __restrict__ bias, void* __restrict__ out0,
    const unsigned short* __restrict__ xraw) {
  __shared__ __align__(16) bf16 sT[4 * RSLOTO];   // 96 KB
  const int bid = blockIdx.x;
  const int swz = (bid & 7) * 32 + (bid >> 3);
  const int bm = (swz >> 3) * 256, bn = (swz & 7) * 128;
  const int N = 1024;

  const floatx4 zero4 = {0.f, 0.f, 0.f, 0.f};
  floatx4 acc[4][4];
#pragma unroll
  for (int i = 0; i < 4; ++i)
#pragma unroll
    for (int j = 0; j < 4; ++j) acc[i][j] = zero4;

  gemm_core128(A, Bt, bm, bn, sT, acc);

  const int tid = threadIdx.x, wave = tid >> 6, lane = tid & 63;
  const int lrow = lane & 15, quad = lane >> 4;
  const int wm = (wave >> 1) << 6, wn = (wave & 1) << 6;
  const int flg = wave_detect_f32(xraw);
#pragma unroll
  for (int i = 0; i < 4; ++i) {
    const int mbase = bm + wm + i * 16 + quad * 4;
#pragma unroll
    for (int j = 0; j < 4; ++j) {
      const int n = bn + wn + j * 16 + lrow;
      const float bv = __bfloat162float(bias[n]);
#pragma unroll
      for (int r = 0; r < 4; ++r) {
        const int m = mbase + r;
        const float fval = acc[i][j][r] + bv;
        const size_t idx = (size_t)m * N + n;
        if (flg) ((float*)out0)[idx] = fval;
        else     ((bf16*)out0)[idx] = __float2bfloat16(fval);
      }
    }
  }
}

// ---------------------------------------------------------------------------
// Attention: 512 thr / 8 waves, padded LDS, per-wave sP (unchanged).
// ---------------------------------------------------------------------------
#define SKP 72
#define SVP 264
__global__ __launch_bounds__(512, 2) void attn_kernel(
    const bf16* __restrict__ qws, const bf16* __restrict__ kws,
    const bf16* __restrict__ vtws, bf16* __restrict__ yws) {
  const int b = blockIdx.z, h = blockIdx.y, qc = blockIdx.x;
  const int bh = b * 16 + h;
  __shared__ __align__(16) bf16 sK[256 * SKP];
  __shared__ __align__(16) bf16 sVt[64 * SVP];
  __shared__ __align__(16) bf16 sP[8][16 * SVP];
  const int tid = threadIdx.x, wave = tid >> 6, lane = tid & 63;
  const int lrow = lane & 15, quad = lane >> 4;
  const bf16* kg = kws + (size_t)bh * (256 * 64);
  const bf16* vg = vtws + (size_t)bh * (64 * 256);
#pragma unroll
  for (int i = 0; i < 4; ++i) {
    const int idx = i * 512 + tid;
    const int kr = idx >> 3, kc = (idx & 7) * 8;
    *(short8*)(sK + kr * SKP + kc) = *(const short8*)(kg + kr * 64 + kc);
    const int vr = idx >> 5, vc = (idx & 31) * 8;
    *(short8*)(sVt + vr * SVP + vc) = *(const short8*)(vg + vr * 256 + vc);
  }
  __syncthreads();
  bf16* sPw = sP[wave];
  const floatx4 zero4 = {0.f, 0.f, 0.f, 0.f};
  const float kscale = 0.18033688011112042f;  // (1/8) * log2(e)

  for (int st = 0; st < 4; ++st) {
    const int t0 = qc * 512 + wave * 64 + st * 16;
    const bf16* qrow = qws + ((size_t)bh * 1024 + t0 + lrow) * 64;
    const short8 aq0 = *(const short8*)(qrow + quad * 8);
    const short8 aq1 = *(const short8*)(qrow + 32 + quad * 8);
    floatx4 sc[16];
#pragma unroll
    for (int nt = 0; nt < 16; ++nt) {
      floatx4 c = zero4;
      c = __builtin_amdgcn_mfma_f32_16x16x32_bf16(
          aq0, *(const short8*)(sK + (nt * 16 + lrow) * SKP + quad * 8), c, 0, 0, 0);
      c = __builtin_amdgcn_mfma_f32_16x16x32_bf16(
          aq1, *(const short8*)(sK + (nt * 16 + lrow) * SKP + 32 + quad * 8), c, 0, 0, 0);
      sc[nt] = c;
    }
    float sum[4] = {0.f, 0.f, 0.f, 0.f};
#pragma unroll
    for (int nt = 0; nt < 16; ++nt) {
      const int s = nt * 16 + lrow;
#pragma unroll
      for (int r = 0; r < 4; ++r) {
        const int t = t0 + quad * 4 + r;
        const float p = (s <= t) ? exp2f(sc[nt][r] * kscale) : 0.f;
        sum[r] += p;
        sPw[(quad * 4 + r) * SVP + nt * 16 + lrow] = __float2bfloat16(p);
      }
    }
#pragma unroll
    for (int r = 0; r < 4; ++r) {
      sum[r] += __shfl_xor(sum[r], 1, 16);
      sum[r] += __shfl_xor(sum[r], 2, 16);
      sum[r] += __shfl_xor(sum[r], 4, 16);
      sum[r] += __shfl_xor(sum[r], 8, 16);
    }
    asm volatile("s_waitcnt lgkmcnt(0)" ::: "memory");
    floatx4 ya[4];
#pragma unroll
    for (int nt = 0; nt < 4; ++nt) ya[nt] = zero4;
#pragma unroll
    for (int ks = 0; ks < 8; ++ks) {
      const short8 ap = *(const short8*)(sPw + lrow * SVP + ks * 32 + quad * 8);
#pragma unroll
      for (int nt = 0; nt < 4; ++nt)
        ya[nt] = __builtin_amdgcn_mfma_f32_16x16x32_bf16(
            ap, *(const short8*)(sVt + (nt * 16 + lrow) * SVP + ks * 32 + quad * 8),
            ya[nt], 0, 0, 0);
    }
#pragma unroll
    for (int r = 0; r < 4; ++r) {
      const float rl = 1.f / sum[r];
      const int t = t0 + quad * 4 + r;
#pragma unroll
      for (int nt = 0; nt < 4; ++nt)
        yws[((size_t)b * 1024 + t) * 1024 + h * 64 + nt * 16 + lrow] =
            __float2bfloat16(ya[nt][r] * rl);
    }
  }
}

// ---------------------------------------------------------------------------
extern "C" void kernel_launch(void* const* d_in, const int* in_sizes, int n_in,
                              void* d_out, int out_size, void* d_ws, size_t ws_size,
                              hipStream_t stream) {
  char* p = (char*)d_ws;
  bf16* cbq   = (bf16*)p;     p += 4096;
  bf16* cbf   = (bf16*)p;     p += 8192;
  bf16* cbp   = (bf16*)p;     p += 4096;
  bf16* weffq = (bf16*)p;     p += (size_t)1024 * 1024 * 2;
  bf16* wefff = (bf16*)p;     p += (size_t)2048 * 1024 * 2;
  bf16* weffp = (bf16*)p;     p += (size_t)1024 * 1024 * 2;
  bf16* qws   = (bf16*)p;     p += (size_t)8 * 16 * 1024 * 64 * 2;
  bf16* kws   = (bf16*)p;     p += (size_t)8 * 16 * 256 * 64 * 2;
  bf16* vtws  = (bf16*)p;     p += (size_t)8 * 16 * 64 * 256 * 2;
  bf16* cft   = (bf16*)p;     p += (size_t)8 * 256 * 1024 * 2;
  bf16* cx    = (bf16*)p;     p += (size_t)8 * 1024 * 1024 * 2;
  bf16* yws   = cx;  // disjoint lifetimes: cx dead after q-proj, yws born in attn
  const size_t required = (size_t)(p - (char*)d_ws);
  if (ws_size < required) return;

  PrepArgs pa;
  pa.x = d_in[0]; pa.ft = d_in[1];
  pa.bq = d_in[3]; pa.bf = d_in[7]; pa.bp = d_in[11];
  pa.Wq = d_in[2];  pa.Aq = d_in[4];  pa.Bq = d_in[5];
  pa.Wf = d_in[6];  pa.Af = d_in[8];  pa.Bf = d_in[9];
  pa.Wp = d_in[10]; pa.Ap = d_in[12]; pa.Bp = d_in[13];
  pa.cx = cx; pa.cft = cft; pa.cbq = cbq; pa.cbf = cbf; pa.cbp = cbp;
  pa.weffq = weffq; pa.wefff = wefff; pa.weffp = weffp;
  prep_kernel<<<9218, 256, 0, stream>>>(pa);

  gemm_qkv<<<192, 512, 0, stream>>>(cx, cft, weffq, wefff, cbq, cbf, qws, kws, vtws);
  attn_kernel<<<dim3(2, 16, 8), 512, 0, stream>>>(qws, kws, vtws, yws);
  gemm_out<<<256, 512, 0, stream>>>(yws, weffp, cbp, d_out, (const unsigned short*)d_in[0]);
}

// Round 4
// 234.790 us; speedup vs baseline: 1.0188x; 1.0188x over previous
//
#include <hip/hip_runtime.h>
#include <hip/hip_bf16.h>
#include <stdint.h>
#include <stddef.h>

typedef __hip_bfloat16 bf16;
typedef __attribute__((ext_vector_type(8))) short short8;   // 8 bf16 = 4 VGPRs
typedef __attribute__((ext_vector_type(4))) float floatx4;  // MFMA 16x16 accumulator

// async global->LDS, 16 B per lane. LDS dest must be wave-uniform base + lane*16.
__device__ __forceinline__ void async_load16(const bf16* g, bf16* l) {
#if defined(__has_builtin) && __has_builtin(__builtin_amdgcn_global_load_lds)
  __builtin_amdgcn_global_load_lds((__attribute__((address_space(1))) void*)g,
                                   (__attribute__((address_space(3))) void*)l,
                                   16, 0, 0);
#else
  *(short8*)l = *(const short8*)g;
#endif
}

// ---------------------------------------------------------------------------
// Wave-local input dtype detection (f32 vs bf16).
// ---------------------------------------------------------------------------
__device__ __forceinline__ int wave_detect_f32(const unsigned short* __restrict__ xr) {
  const int lane = threadIdx.x & 63;
  const unsigned short u = xr[lane];
  const int e = (u >> 7) & 0xFF;
  const unsigned long long m = __ballot(e >= 0x93);
  return (__popcll(m) > 5) ? 1 : 0;
}

// ---------------------------------------------------------------------------
// Fused prep v2: 8-wide canon, 4-wide weff (unchanged from round 3).
// ---------------------------------------------------------------------------
struct PrepArgs {
  const void *x, *ft, *bq, *bf, *bp;
  const void *Wq, *Aq, *Bq, *Wf, *Af, *Bf, *Wp, *Ap, *Bp;
  bf16 *cx, *cft, *cbq, *cbf, *cbp, *weffq, *wefff, *weffp;
};

__device__ __forceinline__ void canon8(const void* src, bf16* dst, int i8, int flg) {
  if (flg) {
    const float4 v0 = ((const float4*)src)[i8 * 2];
    const float4 v1 = ((const float4*)src)[i8 * 2 + 1];
    bf16 o[8];
    o[0] = __float2bfloat16(v0.x); o[1] = __float2bfloat16(v0.y);
    o[2] = __float2bfloat16(v0.z); o[3] = __float2bfloat16(v0.w);
    o[4] = __float2bfloat16(v1.x); o[5] = __float2bfloat16(v1.y);
    o[6] = __float2bfloat16(v1.z); o[7] = __float2bfloat16(v1.w);
    *(uint4*)(dst + i8 * 8) = *(const uint4*)o;
  } else {
    ((uint4*)dst)[i8] = ((const uint4*)src)[i8];
  }
}

// Weff[n][k..k+3] = W + (1/16) * B[n][:] . A[:][k..k+3].  B row is block-uniform.
__device__ __forceinline__ void weff4(const void* W, const void* Bm, const void* Am,
                                      bf16* dst, int idx4, int flg) {
  const int n = idx4 >> 8, k = (idx4 & 255) << 2;
  float a0 = 0.f, a1 = 0.f, a2 = 0.f, a3 = 0.f;
  float w0, w1, w2, w3;
  if (flg) {
    const float* Af = (const float*)Am;
    const float* Bf = (const float*)Bm;
#pragma unroll
    for (int r = 0; r < 16; ++r) {
      const float4 av = *(const float4*)(Af + r * 1024 + k);
      const float bv = Bf[n * 16 + r];
      a0 += bv * av.x; a1 += bv * av.y; a2 += bv * av.z; a3 += bv * av.w;
    }
    const float4 wv = *(const float4*)((const float*)W + n * 1024 + k);
    w0 = wv.x; w1 = wv.y; w2 = wv.z; w3 = wv.w;
  } else {
    const bf16* Ab = (const bf16*)Am;
    const bf16* Bb = (const bf16*)Bm;
#pragma unroll
    for (int r = 0; r < 16; ++r) {
      const float bv = __bfloat162float(Bb[n * 16 + r]);
      const bf16* ap = Ab + r * 1024 + k;
      a0 += bv * __bfloat162float(ap[0]);
      a1 += bv * __bfloat162float(ap[1]);
      a2 += bv * __bfloat162float(ap[2]);
      a3 += bv * __bfloat162float(ap[3]);
    }
    const bf16* Wb = (const bf16*)W + n * 1024 + k;
    w0 = __bfloat162float(Wb[0]); w1 = __bfloat162float(Wb[1]);
    w2 = __bfloat162float(Wb[2]); w3 = __bfloat162float(Wb[3]);
  }
  bf16 o[4];
  o[0] = __float2bfloat16(w0 + 0.0625f * a0);
  o[1] = __float2bfloat16(w1 + 0.0625f * a1);
  o[2] = __float2bfloat16(w2 + 0.0625f * a2);
  o[3] = __float2bfloat16(w3 + 0.0625f * a3);
  *(uint2*)(dst + idx4 * 4) = *(const uint2*)o;
}

// blocks: [0,4096) cx | [4096,5120) cft | [5120,5122) biases |
//         [5122,6146) weffq | [6146,8194) wefff | [8194,9218) weffp
__global__ __launch_bounds__(256) void prep_kernel(PrepArgs a) {
  const int flg = wave_detect_f32((const unsigned short*)a.x);
  const int bid = blockIdx.x, tid = threadIdx.x;
  if (bid < 4096) {
    canon8(a.x, a.cx, bid * 256 + tid, flg);
  } else if (bid < 5120) {
    canon8(a.ft, a.cft, (bid - 4096) * 256 + tid, flg);
  } else if (bid < 5122) {
    const int e8 = (bid - 5120) * 256 + tid;   // 512 threads cover 4096 bias elems
    if (e8 < 128) canon8(a.bq, a.cbq, e8, flg);
    else if (e8 < 384) canon8(a.bf, a.cbf, e8 - 128, flg);
    else canon8(a.bp, a.cbp, e8 - 384, flg);
  } else if (bid < 6146) {
    weff4(a.Wq, a.Bq, a.Aq, a.weffq, (bid - 5122) * 256 + tid, flg);
  } else if (bid < 8194) {
    weff4(a.Wf, a.Bf, a.Af, a.wefff, (bid - 6146) * 256 + tid, flg);
  } else {
    weff4(a.Wp, a.Bp, a.Ap, a.weffp, (bid - 8194) * 256 + tid, flg);
  }
}

// ---------------------------------------------------------------------------
// GEMM core v5: 256x128 tile, BK=32, 4 waves / 256 thr, 3-slot ring (72 KB ->
// 2 blocks/CU), lead-2, counted vmcnt, raw barriers, verified zero-conflict
// XOR chunk swizzle ((r>>1)&3 involution on both sides), and NEW: per-K-step
// TWO-PHASE SPLIT — each phase = {3 stage-issues || ds_reads || 16 MFMA}
// separated by an added mid-barrier (additive barrier: cannot race; vmcnt
// counts re-derived below).
//
// VMEM order per thread: ... [t-1:P0 3][t-1:P1 3][t:P0 3(tile t+2)] <wait>
//   outstanding at wait = 3(t+2 first-half) + 6(t+1) = 9 -> vmcnt(9)
//   confirms all of tile t (issued at iter t-2). Tail: t==30 -> no stage,
//   outstanding = 6 (tile 31) -> vmcnt(6); t==31 -> vmcnt(0).
// Slot safety: stage targets slot (t+2)%3 == slot of tile t-1, whose reads
// all retired before this iter's lgkmcnt(0)+barrier(A).
// ---------------------------------------------------------------------------
#define ASLOT (256 * 32)            // A panel elems
#define BSLOT (128 * 32)            // B panel elems
#define SLOT3 (ASLOT + BSLOT)       // 24 KB per slot

__device__ __forceinline__ void stage_first(const bf16* __restrict__ gA,
                                            const bf16* __restrict__ gB,
                                            bf16* slot, int tid) {
  // A rows 0..127 (2 loads) + B rows 0..63 (1 load)
#pragma unroll
  for (int l = 0; l < 2; ++l) {
    const int D = l * 256 + tid;
    const int r = D >> 2;
    const int c = (D & 3) ^ ((r >> 1) & 3);
    async_load16(gA + (size_t)r * 1024 + c * 8, slot + D * 8);
  }
  {
    const int D = tid;
    const int r = D >> 2;
    const int c = (D & 3) ^ ((r >> 1) & 3);
    async_load16(gB + (size_t)r * 1024 + c * 8, slot + ASLOT + D * 8);
  }
}

__device__ __forceinline__ void stage_second(const bf16* __restrict__ gA,
                                             const bf16* __restrict__ gB,
                                             bf16* slot, int tid) {
  // A rows 128..255 (2 loads) + B rows 64..127 (1 load)
#pragma unroll
  for (int l = 2; l < 4; ++l) {
    const int D = l * 256 + tid;
    const int r = D >> 2;
    const int c = (D & 3) ^ ((r >> 1) & 3);
    async_load16(gA + (size_t)r * 1024 + c * 8, slot + D * 8);
  }
  {
    const int D = 256 + tid;
    const int r = D >> 2;
    const int c = (D & 3) ^ ((r >> 1) & 3);
    async_load16(gB + (size_t)r * 1024 + c * 8, slot + ASLOT + D * 8);
  }
}

__device__ __forceinline__ void gemm_core(const bf16* __restrict__ A,
                                          const bf16* __restrict__ Bt,
                                          int bm, int bn, bf16* sT,
                                          floatx4 (&acc)[8][4]) {
  const int tid = threadIdx.x;
  const int wave = tid >> 6, lane = tid & 63;
  const int lrow = lane & 15, quad = lane >> 4;
  const int wm = (wave >> 1) << 7;      // 2 waves along M: 0,128
  const int wn = (wave & 1) << 6;       // 2 waves along N: 0,64
  const int pc0 = ((quad ^ ((lrow >> 1) & 3)) << 3);  // frag-read XOR

  const bf16* gA = A + (size_t)bm * 1024;
  const bf16* gB = Bt + (size_t)bn * 1024;

  stage_first(gA, gB, sT, tid);  stage_second(gA, gB, sT, tid);              // tile 0
  stage_first(gA + 32, gB + 32, sT + SLOT3, tid);
  stage_second(gA + 32, gB + 32, sT + SLOT3, tid);                           // tile 1

  int rs = 0, ss = 2;
  for (int t = 0; t < 32; ++t) {
    const bf16* slotA = sT + rs * SLOT3;
    const bf16* slotB = slotA + ASLOT;
    bf16* stSlot = sT + ss * SLOT3;
    const bf16* sgA = gA + (t + 2) * 32;
    const bf16* sgB = gB + (t + 2) * 32;

    // (A) all waves retired reads of the slot being re-staged
    asm volatile("s_waitcnt lgkmcnt(0)" ::: "memory");
    __builtin_amdgcn_s_barrier();
    __builtin_amdgcn_sched_barrier(0);
    if (t < 30) {
      stage_first(sgA, sgB, stSlot, tid);
      asm volatile("s_waitcnt vmcnt(9)" ::: "memory");
    } else if (t == 30) {
      asm volatile("s_waitcnt vmcnt(6)" ::: "memory");
    } else {
      asm volatile("s_waitcnt vmcnt(0)" ::: "memory");
    }
    // (B) tile t visible to all waves
    __builtin_amdgcn_s_barrier();
    __builtin_amdgcn_sched_barrier(0);

    // ---- phase 0: A-rows 0..63 of wave block x all 4 B-frags ----
    short8 a_[8], b_[4];
#pragma unroll
    for (int i = 0; i < 4; ++i)
      a_[i] = *(const short8*)(slotA + (wm + i * 16 + lrow) * 32 + pc0);
#pragma unroll
    for (int j = 0; j < 4; ++j)
      b_[j] = *(const short8*)(slotB + (wn + j * 16 + lrow) * 32 + pc0);
    __builtin_amdgcn_s_setprio(1);
#pragma unroll
    for (int i = 0; i < 4; ++i)
#pragma unroll
      for (int j = 0; j < 4; ++j)
        acc[i][j] = __builtin_amdgcn_mfma_f32_16x16x32_bf16(
            a_[i], b_[j], acc[i][j], 0, 0, 0);
    __builtin_amdgcn_s_setprio(0);

    // ---- mid-phase barrier (additive; creates wave role-split) ----
    __builtin_amdgcn_s_barrier();
    __builtin_amdgcn_sched_barrier(0);

    // ---- phase 1: stage second half || A-rows 64..127 x 4 B-frags ----
    if (t < 30) stage_second(sgA, sgB, stSlot, tid);
#pragma unroll
    for (int i = 4; i < 8; ++i)
      a_[i] = *(const short8*)(slotA + (wm + i * 16 + lrow) * 32 + pc0);
    __builtin_amdgcn_s_setprio(1);
#pragma unroll
    for (int i = 4; i < 8; ++i)
#pragma unroll
      for (int j = 0; j < 4; ++j)
        acc[i][j] = __builtin_amdgcn_mfma_f32_16x16x32_bf16(
            a_[i], b_[j], acc[i][j], 0, 0, 0);
    __builtin_amdgcn_s_setprio(0);

    rs = (rs == 2) ? 0 : rs + 1;
    ss = (ss == 2) ? 0 : ss + 1;
  }
}

// ---------------------------------------------------------------------------
// Fused q-proj + kv-proj GEMM: q 32x8 (256) + kv 8x16 (128) = 384 blocks of
// 256x128, bijective XCD swizzle (384 = 8 x 48), 2 blocks/CU capacity.
// ---------------------------------------------------------------------------
__global__ __launch_bounds__(256, 2) void gemm_qkv(
    const bf16* __restrict__ cx, const bf16* __restrict__ cft,
    const bf16* __restrict__ weffq, const bf16* __restrict__ wefff,
    const bf16* __restrict__ cbq, const bf16* __restrict__ cbf,
    bf16* __restrict__ qws, bf16* __restrict__ kws, bf16* __restrict__ vtws) {
  __shared__ __align__(16) bf16 sT[3 * SLOT3];   // 72 KB
  const int bid = blockIdx.x;
  const int swz = (bid & 7) * 48 + (bid >> 3);   // 8 XCDs x 48 contiguous
  int mode, bm, bn;
  const bf16 *A, *Bt, *bias;
  if (swz < 256) {
    mode = 0; A = cx; Bt = weffq; bias = cbq;
    bm = (swz >> 3) * 256; bn = (swz & 7) * 128;
  } else {
    const int s2 = swz - 256;
    mode = 1; A = cft; Bt = wefff; bias = cbf;
    bm = (s2 >> 4) * 256; bn = (s2 & 15) * 128;
  }

  const floatx4 zero4 = {0.f, 0.f, 0.f, 0.f};
  floatx4 acc[8][4];
#pragma unroll
  for (int i = 0; i < 8; ++i)
#pragma unroll
    for (int j = 0; j < 4; ++j) acc[i][j] = zero4;

  gemm_core(A, Bt, bm, bn, sT, acc);

  const int tid = threadIdx.x, wave = tid >> 6, lane = tid & 63;
  const int lrow = lane & 15, quad = lane >> 4;
  const int wm = (wave >> 1) << 7, wn = (wave & 1) << 6;
#pragma unroll
  for (int i = 0; i < 8; ++i) {
    const int mbase = bm + wm + i * 16 + quad * 4;
#pragma unroll
    for (int j = 0; j < 4; ++j) {
      const int n = bn + wn + j * 16 + lrow;
      const float bv = __bfloat162float(bias[n]);
#pragma unroll
      for (int r = 0; r < 4; ++r) {
        const int m = mbase + r;
        const bf16 hval = __float2bfloat16(acc[i][j][r] + bv);
        if (mode == 0) {
          const int b = m >> 10, t = m & 1023, hh = n >> 6, d = n & 63;
          qws[(((size_t)(b * 16 + hh)) * 1024 + t) * 64 + d] = hval;
        } else {
          const int b = m >> 8, s = m & 255;
          if (n < 1024) {
            const int hh = n >> 6, d = n & 63;
            kws[(((size_t)(b * 16 + hh)) * 256 + s) * 64 + d] = hval;
          } else {
            const int nn = n - 1024, hh = nn >> 6, d = nn & 63;
            vtws[(((size_t)(b * 16 + hh)) * 64 + d) * 256 + s] = hval;
          }
        }
      }
    }
  }
}

// ---------------------------------------------------------------------------
// Out-proj GEMM: 32x8 = 256 blocks of 256x128, XCD-swizzled (8 x 32).
// ---------------------------------------------------------------------------
__global__ __launch_bounds__(256, 2) void gemm_out(
    const bf16* __restrict__ A, const bf16* __restrict__ Bt,
    const bf16* __restrict__ bias, void* __restrict__ out0,
    const unsigned short* __restrict__ xraw) {
  __shared__ __align__(16) bf16 sT[3 * SLOT3];
  const int bid = blockIdx.x;
  const int swz = (bid & 7) * 32 + (bid >> 3);
  const int bm = (swz >> 3) * 256, bn = (swz & 7) * 128;
  const int N = 1024;

  const floatx4 zero4 = {0.f, 0.f, 0.f, 0.f};
  floatx4 acc[8][4];
#pragma unroll
  for (int i = 0; i < 8; ++i)
#pragma unroll
    for (int j = 0; j < 4; ++j) acc[i][j] = zero4;

  gemm_core(A, Bt, bm, bn, sT, acc);

  const int tid = threadIdx.x, wave = tid >> 6, lane = tid & 63;
  const int lrow = lane & 15, quad = lane >> 4;
  const int wm = (wave >> 1) << 7, wn = (wave & 1) << 6;
  const int flg = wave_detect_f32(xraw);
#pragma unroll
  for (int i = 0; i < 8; ++i) {
    const int mbase = bm + wm + i * 16 + quad * 4;
#pragma unroll
    for (int j = 0; j < 4; ++j) {
      const int n = bn + wn + j * 16 + lrow;
      const float bv = __bfloat162float(bias[n]);
#pragma unroll
      for (int r = 0; r < 4; ++r) {
        const int m = mbase + r;
        const float fval = acc[i][j][r] + bv;
        const size_t idx = (size_t)m * N + n;
        if (flg) ((float*)out0)[idx] = fval;
        else     ((bf16*)out0)[idx] = __float2bfloat16(fval);
      }
    }
  }
}

// ---------------------------------------------------------------------------
// Attention: 512 thr / 8 waves, padded LDS, per-wave sP (unchanged).
// ---------------------------------------------------------------------------
#define SKP 72
#define SVP 264
__global__ __launch_bounds__(512, 2) void attn_kernel(
    const bf16* __restrict__ qws, const bf16* __restrict__ kws,
    const bf16* __restrict__ vtws, bf16* __restrict__ yws) {
  const int b = blockIdx.z, h = blockIdx.y, qc = blockIdx.x;
  const int bh = b * 16 + h;
  __shared__ __align__(16) bf16 sK[256 * SKP];
  __shared__ __align__(16) bf16 sVt[64 * SVP];
  __shared__ __align__(16) bf16 sP[8][16 * SVP];
  const int tid = threadIdx.x, wave = tid >> 6, lane = tid & 63;
  const int lrow = lane & 15, quad = lane >> 4;
  const bf16* kg = kws + (size_t)bh * (256 * 64);
  const bf16* vg = vtws + (size_t)bh * (64 * 256);
#pragma unroll
  for (int i = 0; i < 4; ++i) {
    const int idx = i * 512 + tid;
    const int kr = idx >> 3, kc = (idx & 7) * 8;
    *(short8*)(sK + kr * SKP + kc) = *(const short8*)(kg + kr * 64 + kc);
    const int vr = idx >> 5, vc = (idx & 31) * 8;
    *(short8*)(sVt + vr * SVP + vc) = *(const short8*)(vg + vr * 256 + vc);
  }
  __syncthreads();
  bf16* sPw = sP[wave];
  const floatx4 zero4 = {0.f, 0.f, 0.f, 0.f};
  const float kscale = 0.18033688011112042f;  // (1/8) * log2(e)

  for (int st = 0; st < 4; ++st) {
    const int t0 = qc * 512 + wave * 64 + st * 16;
    const bf16* qrow = qws + ((size_t)bh * 1024 + t0 + lrow) * 64;
    const short8 aq0 = *(const short8*)(qrow + quad * 8);
    const short8 aq1 = *(const short8*)(qrow + 32 + quad * 8);
    floatx4 sc[16];
#pragma unroll
    for (int nt = 0; nt < 16; ++nt) {
      floatx4 c = zero4;
      c = __builtin_amdgcn_mfma_f32_16x16x32_bf16(
          aq0, *(const short8*)(sK + (nt * 16 + lrow) * SKP + quad * 8), c, 0, 0, 0);
      c = __builtin_amdgcn_mfma_f32_16x16x32_bf16(
          aq1, *(const short8*)(sK + (nt * 16 + lrow) * SKP + 32 + quad * 8), c, 0, 0, 0);
      sc[nt] = c;
    }
    float sum[4] = {0.f, 0.f, 0.f, 0.f};
#pragma unroll
    for (int nt = 0; nt < 16; ++nt) {
      const int s = nt * 16 + lrow;
#pragma unroll
      for (int r = 0; r < 4; ++r) {
        const int t = t0 + quad * 4 + r;
        const float p = (s <= t) ? exp2f(sc[nt][r] * kscale) : 0.f;
        sum[r] += p;
        sPw[(quad * 4 + r) * SVP + nt * 16 + lrow] = __float2bfloat16(p);
      }
    }
#pragma unroll
    for (int r = 0; r < 4; ++r) {
      sum[r] += __shfl_xor(sum[r], 1, 16);
      sum[r] += __shfl_xor(sum[r], 2, 16);
      sum[r] += __shfl_xor(sum[r], 4, 16);
      sum[r] += __shfl_xor(sum[r], 8, 16);
    }
    asm volatile("s_waitcnt lgkmcnt(0)" ::: "memory");
    floatx4 ya[4];
#pragma unroll
    for (int nt = 0; nt < 4; ++nt) ya[nt] = zero4;
#pragma unroll
    for (int ks = 0; ks < 8; ++ks) {
      const short8 ap = *(const short8*)(sPw + lrow * SVP + ks * 32 + quad * 8);
#pragma unroll
      for (int nt = 0; nt < 4; ++nt)
        ya[nt] = __builtin_amdgcn_mfma_f32_16x16x32_bf16(
            ap, *(const short8*)(sVt + (nt * 16 + lrow) * SVP + ks * 32 + quad * 8),
            ya[nt], 0, 0, 0);
    }
#pragma unroll
    for (int r = 0; r < 4; ++r) {
      const float rl = 1.f / sum[r];
      const int t = t0 + quad * 4 + r;
#pragma unroll
      for (int nt = 0; nt < 4; ++nt)
        yws[((size_t)b * 1024 + t) * 1024 + h * 64 + nt * 16 + lrow] =
            __float2bfloat16(ya[nt][r] * rl);
    }
  }
}

// ---------------------------------------------------------------------------
extern "C" void kernel_launch(void* const* d_in, const int* in_sizes, int n_in,
                              void* d_out, int out_size, void* d_ws, size_t ws_size,
                              hipStream_t stream) {
  char* p = (char*)d_ws;
  bf16* cbq   = (bf16*)p;     p += 4096;
  bf16* cbf   = (bf16*)p;     p += 8192;
  bf16* cbp   = (bf16*)p;     p += 4096;
  bf16* weffq = (bf16*)p;     p += (size_t)1024 * 1024 * 2;
  bf16* wefff = (bf16*)p;     p += (size_t)2048 * 1024 * 2;
  bf16* weffp = (bf16*)p;     p += (size_t)1024 * 1024 * 2;
  bf16* qws   = (bf16*)p;     p += (size_t)8 * 16 * 1024 * 64 * 2;
  bf16* kws   = (bf16*)p;     p += (size_t)8 * 16 * 256 * 64 * 2;
  bf16* vtws  = (bf16*)p;     p += (size_t)8 * 16 * 64 * 256 * 2;
  bf16* cft   = (bf16*)p;     p += (size_t)8 * 256 * 1024 * 2;
  bf16* cx    = (bf16*)p;     p += (size_t)8 * 1024 * 1024 * 2;
  bf16* yws   = cx;  // disjoint lifetimes: cx dead after q-proj, yws born in attn
  const size_t required = (size_t)(p - (char*)d_ws);
  if (ws_size < required) return;

  PrepArgs pa;
  pa.x = d_in[0]; pa.ft = d_in[1];
  pa.bq = d_in[3]; pa.bf = d_in[7]; pa.bp = d_in[11];
  pa.Wq = d_in[2];  pa.Aq = d_in[4];  pa.Bq = d_in[5];
  pa.Wf = d_in[6];  pa.Af = d_in[8];  pa.Bf = d_in[9];
  pa.Wp = d_in[10]; pa.Ap = d_in[12]; pa.Bp = d_in[13];
  pa.cx = cx; pa.cft = cft; pa.cbq = cbq; pa.cbf = cbf; pa.cbp = cbp;
  pa.weffq = weffq; pa.wefff = wefff; pa.weffp = weffp;
  prep_kernel<<<9218, 256, 0, stream>>>(pa);

  gemm_qkv<<<384, 256, 0, stream>>>(cx, cft, weffq, wefff, cbq, cbf, qws, kws, vtws);
  attn_kernel<<<dim3(2, 16, 8), 512, 0, stream>>>(qws, kws, vtws, yws);
  gemm_out<<<256, 256, 0, stream>>>(yws, weffp, cbp, d_out, (const unsigned short*)d_in[0]);
}

// Round 5
// 216.082 us; speedup vs baseline: 1.1070x; 1.0866x over previous
//
#include <hip/hip_runtime.h>
#include <hip/hip_bf16.h>
#include <stdint.h>
#include <stddef.h>

typedef __hip_bfloat16 bf16;
typedef __attribute__((ext_vector_type(8))) short short8;   // 8 bf16 = 4 VGPRs
typedef __attribute__((ext_vector_type(4))) float floatx4;  // MFMA 16x16 accumulator

// async global->LDS, 16 B per lane. LDS dest must be wave-uniform base + lane*16.
__device__ __forceinline__ void async_load16(const bf16* g, bf16* l) {
#if defined(__has_builtin) && __has_builtin(__builtin_amdgcn_global_load_lds)
  __builtin_amdgcn_global_load_lds((__attribute__((address_space(1))) void*)g,
                                   (__attribute__((address_space(3))) void*)l,
                                   16, 0, 0);
#else
  *(short8*)l = *(const short8*)g;
#endif
}

// ---------------------------------------------------------------------------
// Wave-local input dtype detection (f32 vs bf16).
// ---------------------------------------------------------------------------
__device__ __forceinline__ int wave_detect_f32(const unsigned short* __restrict__ xr) {
  const int lane = threadIdx.x & 63;
  const unsigned short u = xr[lane];
  const int e = (u >> 7) & 0xFF;
  const unsigned long long m = __ballot(e >= 0x93);
  return (__popcll(m) > 5) ? 1 : 0;
}

// ---------------------------------------------------------------------------
// Fused prep v2: 8-wide canon, 4-wide weff (kept from rounds 3-4 — left the
// profile top-5, i.e. improved from 44.3 us).
// ---------------------------------------------------------------------------
struct PrepArgs {
  const void *x, *ft, *bq, *bf, *bp;
  const void *Wq, *Aq, *Bq, *Wf, *Af, *Bf, *Wp, *Ap, *Bp;
  bf16 *cx, *cft, *cbq, *cbf, *cbp, *weffq, *wefff, *weffp;
};

__device__ __forceinline__ void canon8(const void* src, bf16* dst, int i8, int flg) {
  if (flg) {
    const float4 v0 = ((const float4*)src)[i8 * 2];
    const float4 v1 = ((const float4*)src)[i8 * 2 + 1];
    bf16 o[8];
    o[0] = __float2bfloat16(v0.x); o[1] = __float2bfloat16(v0.y);
    o[2] = __float2bfloat16(v0.z); o[3] = __float2bfloat16(v0.w);
    o[4] = __float2bfloat16(v1.x); o[5] = __float2bfloat16(v1.y);
    o[6] = __float2bfloat16(v1.z); o[7] = __float2bfloat16(v1.w);
    *(uint4*)(dst + i8 * 8) = *(const uint4*)o;
  } else {
    ((uint4*)dst)[i8] = ((const uint4*)src)[i8];
  }
}

// Weff[n][k..k+3] = W + (1/16) * B[n][:] . A[:][k..k+3].  B row is block-uniform.
__device__ __forceinline__ void weff4(const void* W, const void* Bm, const void* Am,
                                      bf16* dst, int idx4, int flg) {
  const int n = idx4 >> 8, k = (idx4 & 255) << 2;
  float a0 = 0.f, a1 = 0.f, a2 = 0.f, a3 = 0.f;
  float w0, w1, w2, w3;
  if (flg) {
    const float* Af = (const float*)Am;
    const float* Bf = (const float*)Bm;
#pragma unroll
    for (int r = 0; r < 16; ++r) {
      const float4 av = *(const float4*)(Af + r * 1024 + k);
      const float bv = Bf[n * 16 + r];
      a0 += bv * av.x; a1 += bv * av.y; a2 += bv * av.z; a3 += bv * av.w;
    }
    const float4 wv = *(const float4*)((const float*)W + n * 1024 + k);
    w0 = wv.x; w1 = wv.y; w2 = wv.z; w3 = wv.w;
  } else {
    const bf16* Ab = (const bf16*)Am;
    const bf16* Bb = (const bf16*)Bm;
#pragma unroll
    for (int r = 0; r < 16; ++r) {
      const float bv = __bfloat162float(Bb[n * 16 + r]);
      const bf16* ap = Ab + r * 1024 + k;
      a0 += bv * __bfloat162float(ap[0]);
      a1 += bv * __bfloat162float(ap[1]);
      a2 += bv * __bfloat162float(ap[2]);
      a3 += bv * __bfloat162float(ap[3]);
    }
    const bf16* Wb = (const bf16*)W + n * 1024 + k;
    w0 = __bfloat162float(Wb[0]); w1 = __bfloat162float(Wb[1]);
    w2 = __bfloat162float(Wb[2]); w3 = __bfloat162float(Wb[3]);
  }
  bf16 o[4];
  o[0] = __float2bfloat16(w0 + 0.0625f * a0);
  o[1] = __float2bfloat16(w1 + 0.0625f * a1);
  o[2] = __float2bfloat16(w2 + 0.0625f * a2);
  o[3] = __float2bfloat16(w3 + 0.0625f * a3);
  *(uint2*)(dst + idx4 * 4) = *(const uint2*)o;
}

// blocks: [0,4096) cx | [4096,5120) cft | [5120,5122) biases |
//         [5122,6146) weffq | [6146,8194) wefff | [8194,9218) weffp
__global__ __launch_bounds__(256) void prep_kernel(PrepArgs a) {
  const int flg = wave_detect_f32((const unsigned short*)a.x);
  const int bid = blockIdx.x, tid = threadIdx.x;
  if (bid < 4096) {
    canon8(a.x, a.cx, bid * 256 + tid, flg);
  } else if (bid < 5120) {
    canon8(a.ft, a.cft, (bid - 4096) * 256 + tid, flg);
  } else if (bid < 5122) {
    const int e8 = (bid - 5120) * 256 + tid;
    if (e8 < 128) canon8(a.bq, a.cbq, e8, flg);
    else if (e8 < 384) canon8(a.bf, a.cbf, e8 - 128, flg);
    else canon8(a.bp, a.cbp, e8 - 384, flg);
  } else if (bid < 6146) {
    weff4(a.Wq, a.Bq, a.Aq, a.weffq, (bid - 5122) * 256 + tid, flg);
  } else if (bid < 8194) {
    weff4(a.Wf, a.Bf, a.Af, a.wefff, (bid - 6146) * 256 + tid, flg);
  } else {
    weff4(a.Wp, a.Bp, a.Ap, a.weffp, (bid - 8194) * 256 + tid, flg);
  }
}

// ---------------------------------------------------------------------------
// GEMM core (round-2 verified: 42.7 us qkv, 604 TF, 0 bank conflicts):
// 128x128 tile, BK=32, 256 thr / 4 waves, 3-slot LDS ring (48 KB -> 3
// blocks/CU TLP), counted vmcnt (never 0 in steady state), raw s_barrier,
// zero-conflict XOR chunk swizzle (chunk ^= (row>>1)&3, both sides), setprio.
// Rounds 3-4 falsified bigger-tile / phase-split variants (grid fill + sync
// overhead dominate); TLP + balanced fill is what measures fastest.
// ---------------------------------------------------------------------------
#define SLOT ((128 + 128) * 32)   // elements per slot: A 128x32 then B 128x32

__device__ __forceinline__ void stage_slot(const bf16* __restrict__ gA,
                                           const bf16* __restrict__ gB,
                                           bf16* slot, int tid) {
#pragma unroll
  for (int l = 0; l < 2; ++l) {
    const int D = l * 256 + tid;
    const int r = D >> 2;
    const int c = (D & 3) ^ ((r >> 1) & 3);
    async_load16(gA + (size_t)r * 1024 + c * 8, slot + D * 8);
  }
#pragma unroll
  for (int l = 0; l < 2; ++l) {
    const int D = l * 256 + tid;
    const int r = D >> 2;
    const int c = (D & 3) ^ ((r >> 1) & 3);
    async_load16(gB + (size_t)r * 1024 + c * 8, slot + 128 * 32 + D * 8);
  }
}

__device__ __forceinline__ void gemm_core(const bf16* __restrict__ A,
                                          const bf16* __restrict__ Bt,
                                          int bm, int bn, bf16* sT,
                                          floatx4 (&acc)[4][4]) {
  const int tid = threadIdx.x;
  const int wave = tid >> 6, lane = tid & 63;
  const int lrow = lane & 15, quad = lane >> 4;
  const int wm64 = (wave >> 1) << 6;   // 2 waves along M: 0,64
  const int wn64 = (wave & 1) << 6;    // 2 waves along N: 0,64
  const int pc0 = ((quad ^ ((lrow >> 1) & 3)) << 3);

  const bf16* gA = A + (size_t)bm * 1024;
  const bf16* gB = Bt + (size_t)bn * 1024;

  stage_slot(gA, gB, sT, tid);                    // tile 0 -> slot 0
  stage_slot(gA + 32, gB + 32, sT + SLOT, tid);   // tile 1 -> slot 1

#pragma unroll
  for (int t = 0; t < 32; ++t) {
    // (A) all waves done READING slot (t+2)%3 (== slot of tile t-1)
    asm volatile("s_waitcnt lgkmcnt(0)" ::: "memory");
    __builtin_amdgcn_s_barrier();
    __builtin_amdgcn_sched_barrier(0);
    if (t < 30) {
      stage_slot(gA + (t + 2) * 32, gB + (t + 2) * 32,
                 sT + ((t + 2) % 3) * SLOT, tid);
      asm volatile("s_waitcnt vmcnt(8)" ::: "memory");   // tile t landed
    } else if (t == 30) {
      asm volatile("s_waitcnt vmcnt(4)" ::: "memory");
    } else {
      asm volatile("s_waitcnt vmcnt(0)" ::: "memory");
    }
    // (B) tile t visible to ALL waves
    __builtin_amdgcn_s_barrier();
    __builtin_amdgcn_sched_barrier(0);

    const bf16* slotA = sT + (t % 3) * SLOT;
    const bf16* slotB = slotA + 128 * 32;
    short8 a_[4], b_[4];
#pragma unroll
    for (int i = 0; i < 4; ++i) {
      a_[i] = *(const short8*)(slotA + (wm64 + i * 16 + lrow) * 32 + pc0);
      b_[i] = *(const short8*)(slotB + (wn64 + i * 16 + lrow) * 32 + pc0);
    }
    __builtin_amdgcn_s_setprio(1);
#pragma unroll
    for (int i = 0; i < 4; ++i)
#pragma unroll
      for (int j = 0; j < 4; ++j)
        acc[i][j] = __builtin_amdgcn_mfma_f32_16x16x32_bf16(
            a_[i], b_[j], acc[i][j], 0, 0, 0);
    __builtin_amdgcn_s_setprio(0);
  }
}

// ---------------------------------------------------------------------------
// Fused q-proj + kv-proj GEMM, 768 blocks = exactly 3/CU, XCD-swizzled
// (round-0/2 verified mapping).
// ---------------------------------------------------------------------------
__global__ __launch_bounds__(256, 3) void gemm_qkv(
    const bf16* __restrict__ cx, const bf16* __restrict__ cft,
    const bf16* __restrict__ weffq, const bf16* __restrict__ wefff,
    const bf16* __restrict__ cbq, const bf16* __restrict__ cbf,
    bf16* __restrict__ qws, bf16* __restrict__ kws, bf16* __restrict__ vtws) {
  __shared__ __align__(16) bf16 sT[3 * SLOT];   // 48 KB
  const int bid = blockIdx.x;
  int mode, bm, bn;
  const bf16 *A, *Bt, *bias;
  if (bid < 512) {
    mode = 0; A = cx; Bt = weffq; bias = cbq;
    bm = (((bid & 7) << 3) | ((bid >> 3) & 7)) * 128;
    bn = (bid >> 6) * 128;
  } else {
    const int b2 = bid - 512;
    mode = 1; A = cft; Bt = wefff; bias = cbf;
    bm = (((b2 & 7) << 1) | ((b2 >> 3) & 1)) * 128;
    bn = (b2 >> 4) * 128;
  }

  const floatx4 zero4 = {0.f, 0.f, 0.f, 0.f};
  floatx4 acc[4][4];
#pragma unroll
  for (int i = 0; i < 4; ++i)
#pragma unroll
    for (int j = 0; j < 4; ++j) acc[i][j] = zero4;

  gemm_core(A, Bt, bm, bn, sT, acc);

  const int tid = threadIdx.x, wave = tid >> 6, lane = tid & 63;
  const int lrow = lane & 15, quad = lane >> 4;
  const int wm64 = (wave >> 1) << 6, wn64 = (wave & 1) << 6;
#pragma unroll
  for (int i = 0; i < 4; ++i) {
    const int mbase = bm + wm64 + i * 16 + quad * 4;
#pragma unroll
    for (int j = 0; j < 4; ++j) {
      const int n = bn + wn64 + j * 16 + lrow;
      const float bv = __bfloat162float(bias[n]);
#pragma unroll
      for (int r = 0; r < 4; ++r) {
        const int m = mbase + r;
        const bf16 hval = __float2bfloat16(acc[i][j][r] + bv);
        if (mode == 0) {
          const int b = m >> 10, t = m & 1023, hh = n >> 6, d = n & 63;
          qws[(((size_t)(b * 16 + hh)) * 1024 + t) * 64 + d] = hval;
        } else {
          const int b = m >> 8, s = m & 255;
          if (n < 1024) {
            const int hh = n >> 6, d = n & 63;
            kws[(((size_t)(b * 16 + hh)) * 256 + s) * 64 + d] = hval;
          } else {
            const int nn = n - 1024, hh = nn >> 6, d = nn & 63;
            vtws[(((size_t)(b * 16 + hh)) * 64 + d) * 256 + s] = hval;
          }
        }
      }
    }
  }
}

// ---------------------------------------------------------------------------
// Out-proj GEMM: 512 blocks (2/CU, balanced), XCD-swizzled.
// ---------------------------------------------------------------------------
__global__ __launch_bounds__(256, 3) void gemm_out(
    const bf16* __restrict__ A, const bf16* __restrict__ Bt,
    const bf16* __restrict__ bias, void* __restrict__ out0,
    const unsigned short* __restrict__ xraw) {
  __shared__ __align__(16) bf16 sT[3 * SLOT];
  const int bid = blockIdx.x;
  const int bm = (((bid & 7) << 3) | ((bid >> 3) & 7)) * 128;
  const int bn = (bid >> 6) * 128;
  const int N = 1024;

  const floatx4 zero4 = {0.f, 0.f, 0.f, 0.f};
  floatx4 acc[4][4];
#pragma unroll
  for (int i = 0; i < 4; ++i)
#pragma unroll
    for (int j = 0; j < 4; ++j) acc[i][j] = zero4;

  gemm_core(A, Bt, bm, bn, sT, acc);

  const int tid = threadIdx.x, wave = tid >> 6, lane = tid & 63;
  const int lrow = lane & 15, quad = lane >> 4;
  const int wm64 = (wave >> 1) << 6, wn64 = (wave & 1) << 6;
  const int flg = wave_detect_f32(xraw);
#pragma unroll
  for (int i = 0; i < 4; ++i) {
    const int mbase = bm + wm64 + i * 16 + quad * 4;
#pragma unroll
    for (int j = 0; j < 4; ++j) {
      const int n = bn + wn64 + j * 16 + lrow;
      const float bv = __bfloat162float(bias[n]);
#pragma unroll
      for (int r = 0; r < 4; ++r) {
        const int m = mbase + r;
        const float fval = acc[i][j][r] + bv;
        const size_t idx = (size_t)m * N + n;
        if (flg) ((float*)out0)[idx] = fval;
        else     ((bf16*)out0)[idx] = __float2bfloat16(fval);
      }
    }
  }
}

// ---------------------------------------------------------------------------
// Attention: 512 thr / 8 waves, padded LDS, per-wave sP (unchanged — will
// surface in the next profile's top-5 for targeted optimization).
// ---------------------------------------------------------------------------
#define SKP 72
#define SVP 264
__global__ __launch_bounds__(512, 2) void attn_kernel(
    const bf16* __restrict__ qws, const bf16* __restrict__ kws,
    const bf16* __restrict__ vtws, bf16* __restrict__ yws) {
  const int b = blockIdx.z, h = blockIdx.y, qc = blockIdx.x;
  const int bh = b * 16 + h;
  __shared__ __align__(16) bf16 sK[256 * SKP];
  __shared__ __align__(16) bf16 sVt[64 * SVP];
  __shared__ __align__(16) bf16 sP[8][16 * SVP];
  const int tid = threadIdx.x, wave = tid >> 6, lane = tid & 63;
  const int lrow = lane & 15, quad = lane >> 4;
  const bf16* kg = kws + (size_t)bh * (256 * 64);
  const bf16* vg = vtws + (size_t)bh * (64 * 256);
#pragma unroll
  for (int i = 0; i < 4; ++i) {
    const int idx = i * 512 + tid;
    const int kr = idx >> 3, kc = (idx & 7) * 8;
    *(short8*)(sK + kr * SKP + kc) = *(const short8*)(kg + kr * 64 + kc);
    const int vr = idx >> 5, vc = (idx & 31) * 8;
    *(short8*)(sVt + vr * SVP + vc) = *(const short8*)(vg + vr * 256 + vc);
  }
  __syncthreads();
  bf16* sPw = sP[wave];
  const floatx4 zero4 = {0.f, 0.f, 0.f, 0.f};
  const float kscale = 0.18033688011112042f;  // (1/8) * log2(e)

  for (int st = 0; st < 4; ++st) {
    const int t0 = qc * 512 + wave * 64 + st * 16;
    const bf16* qrow = qws + ((size_t)bh * 1024 + t0 + lrow) * 64;
    const short8 aq0 = *(const short8*)(qrow + quad * 8);
    const short8 aq1 = *(const short8*)(qrow + 32 + quad * 8);
    floatx4 sc[16];
#pragma unroll
    for (int nt = 0; nt < 16; ++nt) {
      floatx4 c = zero4;
      c = __builtin_amdgcn_mfma_f32_16x16x32_bf16(
          aq0, *(const short8*)(sK + (nt * 16 + lrow) * SKP + quad * 8), c, 0, 0, 0);
      c = __builtin_amdgcn_mfma_f32_16x16x32_bf16(
          aq1, *(const short8*)(sK + (nt * 16 + lrow) * SKP + 32 + quad * 8), c, 0, 0, 0);
      sc[nt] = c;
    }
    float sum[4] = {0.f, 0.f, 0.f, 0.f};
#pragma unroll
    for (int nt = 0; nt < 16; ++nt) {
      const int s = nt * 16 + lrow;
#pragma unroll
      for (int r = 0; r < 4; ++r) {
        const int t = t0 + quad * 4 + r;
        const float p = (s <= t) ? exp2f(sc[nt][r] * kscale) : 0.f;
        sum[r] += p;
        sPw[(quad * 4 + r) * SVP + nt * 16 + lrow] = __float2bfloat16(p);
      }
    }
#pragma unroll
    for (int r = 0; r < 4; ++r) {
      sum[r] += __shfl_xor(sum[r], 1, 16);
      sum[r] += __shfl_xor(sum[r], 2, 16);
      sum[r] += __shfl_xor(sum[r], 4, 16);
      sum[r] += __shfl_xor(sum[r], 8, 16);
    }
    asm volatile("s_waitcnt lgkmcnt(0)" ::: "memory");
    floatx4 ya[4];
#pragma unroll
    for (int nt = 0; nt < 4; ++nt) ya[nt] = zero4;
#pragma unroll
    for (int ks = 0; ks < 8; ++ks) {
      const short8 ap = *(const short8*)(sPw + lrow * SVP + ks * 32 + quad * 8);
#pragma unroll
      for (int nt = 0; nt < 4; ++nt)
        ya[nt] = __builtin_amdgcn_mfma_f32_16x16x32_bf16(
            ap, *(const short8*)(sVt + (nt * 16 + lrow) * SVP + ks * 32 + quad * 8),
            ya[nt], 0, 0, 0);
    }
#pragma unroll
    for (int r = 0; r < 4; ++r) {
      const float rl = 1.f / sum[r];
      const int t = t0 + quad * 4 + r;
#pragma unroll
      for (int nt = 0; nt < 4; ++nt)
        yws[((size_t)b * 1024 + t) * 1024 + h * 64 + nt * 16 + lrow] =
            __float2bfloat16(ya[nt][r] * rl);
    }
  }
}

// ---------------------------------------------------------------------------
extern "C" void kernel_launch(void* const* d_in, const int* in_sizes, int n_in,
                              void* d_out, int out_size, void* d_ws, size_t ws_size,
                              hipStream_t stream) {
  char* p = (char*)d_ws;
  bf16* cbq   = (bf16*)p;     p += 4096;
  bf16* cbf   = (bf16*)p;     p += 8192;
  bf16* cbp   = (bf16*)p;     p += 4096;
  bf16* weffq = (bf16*)p;     p += (size_t)1024 * 1024 * 2;
  bf16* wefff = (bf16*)p;     p += (size_t)2048 * 1024 * 2;
  bf16* weffp = (bf16*)p;     p += (size_t)1024 * 1024 * 2;
  bf16* qws   = (bf16*)p;     p += (size_t)8 * 16 * 1024 * 64 * 2;
  bf16* kws   = (bf16*)p;     p += (size_t)8 * 16 * 256 * 64 * 2;
  bf16* vtws  = (bf16*)p;     p += (size_t)8 * 16 * 64 * 256 * 2;
  bf16* cft   = (bf16*)p;     p += (size_t)8 * 256 * 1024 * 2;
  bf16* cx    = (bf16*)p;     p += (size_t)8 * 1024 * 1024 * 2;
  bf16* yws   = cx;  // disjoint lifetimes: cx dead after q-proj, yws born in attn
  const size_t required = (size_t)(p - (char*)d_ws);
  if (ws_size < required) return;

  PrepArgs pa;
  pa.x = d_in[0]; pa.ft = d_in[1];
  pa.bq = d_in[3]; pa.bf = d_in[7]; pa.bp = d_in[11];
  pa.Wq = d_in[2];  pa.Aq = d_in[4];  pa.Bq = d_in[5];
  pa.Wf = d_in[6];  pa.Af = d_in[8];  pa.Bf = d_in[9];
  pa.Wp = d_in[10]; pa.Ap = d_in[12]; pa.Bp = d_in[13];
  pa.cx = cx; pa.cft = cft; pa.cbq = cbq; pa.cbf = cbf; pa.cbp = cbp;
  pa.weffq = weffq; pa.wefff = wefff; pa.weffp = weffp;
  prep_kernel<<<9218, 256, 0, stream>>>(pa);

  gemm_qkv<<<768, 256, 0, stream>>>(cx, cft, weffq, wefff, cbq, cbf, qws, kws, vtws);
  attn_kernel<<<dim3(2, 16, 8), 512, 0, stream>>>(qws, kws, vtws, yws);
  gemm_out<<<512, 256, 0, stream>>>(yws, weffp, cbp, d_out, (const unsigned short*)d_in[0]);
}